// Round 5
// baseline (317.594 us; speedup 1.0000x reference)
//
#include <hip/hip_runtime.h>
#include <hip/hip_cooperative_groups.h>

namespace cg = cooperative_groups;

#define N_NODES  100000
#define N_EDGES  1600000
#define HIDDEN   128
#define N_GRAPHS 2048
#define VOCAB    28
#define NB       256        // dst buckets of 392 nodes = grid size (1 block/CU)
#define NPB      392        // nodes per bucket
#define CAP      7000       // per-bucket capacity (E=6250, sigma~79 -> +9.5σ)
#define EPB      6250       // edges per block (256*6250 = 1.6M exact)
#define EPT      7          // ceil(6250/1024)
#define CSTR     29         // lcnt stride (gcd(29,32)=1 -> conflict-free)
#define MAGIC    2804876602ULL  // ceil(2^40/392): b=(dst*MAGIC)>>40 exact for dst<2.8e5

// ---------------------------------------------------------------------------
// One cooperative kernel, 4 phases separated by grid.sync():
//  P0 zero gcursor+y_hat | P1 bin (blk0: weight folds) | P2 layer0 | P3 layer1
// LDS: single 45.5 KB arena aliased per phase. No early returns (grid.sync).
// ---------------------------------------------------------------------------
__global__ __launch_bounds__(1024) void k_fused(
    const int* __restrict__ esrc, const int* __restrict__ edst,
    const int* __restrict__ x_idx, const int* __restrict__ batch,
    const float* __restrict__ embed, const float* __restrict__ eps0,
    const float* __restrict__ w1_0, const float* __restrict__ b1_0,
    const float* __restrict__ w2_0, const float* __restrict__ b2_0,
    const float* __restrict__ eps1,
    const float* __restrict__ w1_1, const float* __restrict__ b1_1,
    const float* __restrict__ w2_1, const float* __restrict__ b2_1,
    unsigned* __restrict__ binned, int* __restrict__ gcursor,
    float* __restrict__ dvec, float* __restrict__ EW,
    float* __restrict__ bc0, float* __restrict__ wc1,
    float* __restrict__ bc1, float* __restrict__ out)
{
    cg::grid_group grid = cg::this_grid();
    __shared__ int smem[NPB * CSTR];            // 45.5 KB arena

    const int tid = threadIdx.x;
    const int bid = blockIdx.x;

    // ---------------- P0: zero gcursor + y_hat ----------------
    if (tid == 0) gcursor[bid] = 0;
    if (bid < 2) out[bid * 1024 + tid] = 0.f;   // 2048 = 2*1024 exact
    grid.sync();

    // ---------------- P1: scan-free direct-scatter binning ----------------
    {
        int* hist  = smem;              // [256]
        int* lcur  = smem + 256;        // [256]
        int* gbase = smem + 512;        // [256]
        if (tid < NB) { hist[tid] = 0; lcur[tid] = 0; }
        __syncthreads();

        unsigned mypk[EPT];
        short    myb[EPT];
#pragma unroll
        for (int i = 0; i < EPT; ++i) {
            int idx = i * 1024 + tid;
            myb[i] = -1;
            if (idx < EPB) {
                int e   = bid * EPB + idx;
                int dst = edst[e];
                int src = esrc[e];
                int b   = (int)(((unsigned long long)dst * MAGIC) >> 40);
                int dl  = dst - b * NPB;                  // 0..391 (9 bits)
                int vix = x_idx[src];                     // 5 bits
                mypk[i] = ((unsigned)dl << 22) | ((unsigned)vix << 17) | (unsigned)src;
                myb[i]  = (short)b;
                atomicAdd(&hist[b], 1);
            }
        }
        __syncthreads();

        if (tid < NB) {
            int v = hist[tid];
            gbase[tid] = (v > 0) ? atomicAdd(&gcursor[tid], v) : 0;
        }
        __syncthreads();

#pragma unroll
        for (int i = 0; i < EPT; ++i) {
            if (myb[i] >= 0) {
                int b  = myb[i];
                int lr = atomicAdd(&lcur[b], 1);
                binned[(size_t)b * CAP + gbase[b] + lr] = mypk[i];
            }
        }

        // block 0: weight folds (region smem+1024.. disjoint from hist/lcur/gbase)
        if (bid == 0) {
            float* Tl = reinterpret_cast<float*>(smem + 1024);   // [3584]
            for (int g = tid; g < VOCAB * HIDDEN; g += 1024) {
                int i = g >> 7, j = g & 127;
                float s = 0.f;
#pragma unroll 8
                for (int k = 0; k < HIDDEN; ++k)
                    s += embed[i * HIDDEN + k] * w1_0[k * HIDDEN + j];
                Tl[g] = s;
            }
            __syncthreads();
            for (int g = tid; g < VOCAB * HIDDEN; g += 1024) {
                int i = g >> 7, j = g & 127;
                float s = 0.f;
#pragma unroll 8
                for (int k = 0; k < HIDDEN; ++k)
                    s += Tl[i * HIDDEN + k] * w2_0[k * HIDDEN + j];
                EW[g] = s;
            }
            if (tid < 128) {
                float s = 0.f;
#pragma unroll 8
                for (int k = 0; k < HIDDEN; ++k)
                    s += b1_0[k] * w2_0[k * HIDDEN + tid];
                bc0[tid] = s + b2_0[tid];
                if (tid == 0) {
                    float q = 0.f;
                    for (int k = 0; k < HIDDEN; ++k) q += b1_1[k] * w2_1[k];
                    bc1[0] = q + b2_1[0];
                }
            } else if (tid < 256) {
                int i = tid - 128;
                float s = 0.f;
#pragma unroll 8
                for (int k = 0; k < HIDDEN; ++k)
                    s += w1_1[i * HIDDEN + k] * w2_1[k];
                wc1[i] = s;
            }
        }
    }
    grid.sync();

    // ---------------- P2: layer 0 (+dot wc1) ----------------
    {
        int* lcnt = smem;                                // [NPB*CSTR]
        for (int i = tid; i < NPB * CSTR; i += 1024) lcnt[i] = 0;
        __syncthreads();

        const int cnt = gcursor[bid];
        const unsigned* bp = binned + (size_t)bid * CAP;
        for (int i = tid; i < cnt; i += 1024) {
            unsigned pk = bp[i];
            atomicAdd(&lcnt[(pk >> 22) * CSTR + ((pk >> 17) & 31)], 1);
        }
        __syncthreads();

        if (tid < NPB) {
            const int n      = bid * NPB + tid;
            const bool valid = (n < N_NODES);
            const int xi     = valid ? x_idx[n] : 0;
            const float s    = 1.0f + eps0[0];

            float cf[VOCAB];
#pragma unroll
            for (int v = 0; v < VOCAB; ++v)
                cf[v] = (float)lcnt[tid * CSTR + v] + ((v == xi) ? s : 0.0f);

            const float4* EW4 = reinterpret_cast<const float4*>(EW);  // uniform
            const float4* b04 = reinterpret_cast<const float4*>(bc0);
            const float4* w14 = reinterpret_cast<const float4*>(wc1);

            float dacc = 0.f;
#pragma unroll 1
            for (int f4 = 0; f4 < 32; ++f4) {
                float4 a = b04[f4];
#pragma unroll
                for (int v = 0; v < VOCAB; ++v) {
                    float4 e = EW4[v * 32 + f4];
                    a.x += cf[v] * e.x;
                    a.y += cf[v] * e.y;
                    a.z += cf[v] * e.z;
                    a.w += cf[v] * e.w;
                }
                float4 w = w14[f4];
                dacc += fmaxf(a.x, 0.f) * w.x + fmaxf(a.y, 0.f) * w.y
                      + fmaxf(a.z, 0.f) * w.z + fmaxf(a.w, 0.f) * w.w;
            }
            if (valid) dvec[n] = dacc;
        }
    }
    grid.sync();

    // ---------------- P3: layer 1 aggregation + fused outputs ----------------
    {
        float* racc = reinterpret_cast<float*>(smem);        // [392]
        float* gacc = reinterpret_cast<float*>(smem + 512);  // [2048]
        const int n0    = bid * NPB;
        const int nlast = min(n0 + NPB - 1, N_NODES - 1);

        if (tid < NPB) racc[tid] = 0.f;
        const int g0 = batch[n0];
        const int g1 = batch[nlast];
        for (int g = g0 + tid; g <= g1; g += 1024) gacc[g] = 0.f;
        __syncthreads();

        const int cnt = gcursor[bid];
        const unsigned* bp = binned + (size_t)bid * CAP;
        for (int i = tid; i < cnt; i += 1024) {
            unsigned pk = bp[i];
            atomicAdd(&racc[pk >> 22], dvec[pk & 0x1FFFFu]);
        }
        __syncthreads();

        int n = n0 + tid;
        if (tid < NPB && n < N_NODES) {
            float r = (1.0f + eps1[0]) * dvec[n] + racc[tid] + bc1[0];
            out[N_GRAPHS + n] = r;
            atomicAdd(&gacc[batch[n]], r);
        }
        __syncthreads();
        for (int g = g0 + tid; g <= g1; g += 1024) {
            float v = gacc[g];
            if (v != 0.f) atomicAdd(&out[g], v);
        }
    }
}

// ---------------------------------------------------------------------------
extern "C" void kernel_launch(void* const* d_in, const int* in_sizes, int n_in,
                              void* d_out, int out_size, void* d_ws, size_t ws_size,
                              hipStream_t stream) {
    const int*   x_idx = (const int*)d_in[0];
    const int*   esrc  = (const int*)d_in[1];
    const int*   edst  = (const int*)d_in[2];
    const int*   batch = (const int*)d_in[3];
    const float* embed = (const float*)d_in[4];
    const float* eps0  = (const float*)d_in[5];
    const float* w1_0  = (const float*)d_in[6];
    const float* b1_0  = (const float*)d_in[7];
    const float* w2_0  = (const float*)d_in[8];
    const float* b2_0  = (const float*)d_in[9];
    const float* eps1  = (const float*)d_in[10];
    const float* w1_1  = (const float*)d_in[11];
    const float* b1_1  = (const float*)d_in[12];
    const float* w2_1  = (const float*)d_in[13];
    const float* b2_1  = (const float*)d_in[14];

    float* out = (float*)d_out;

    // ws: [gcursor(512) | binned(NB*CAP) | dvec(100352) | EW(3584) | bc0 | wc1 | bc1]
    // (bc1 last so EW/bc0/wc1 stay 16B-aligned)
    int*      gcursor = (int*)d_ws;                           // 512 ints
    unsigned* binned  = (unsigned*)(gcursor + 512);           // NB*CAP
    float*    dvec    = (float*)(binned + (size_t)NB * CAP);  // 100352
    float*    EW      = dvec + 100352;                        // 3584
    float*    bc0     = EW + VOCAB * HIDDEN;                  // 128
    float*    wc1     = bc0 + HIDDEN;                         // 128
    float*    bc1     = wc1 + HIDDEN;                         // 1

    void* args[] = {
        (void*)&esrc, (void*)&edst, (void*)&x_idx, (void*)&batch,
        (void*)&embed, (void*)&eps0,
        (void*)&w1_0, (void*)&b1_0, (void*)&w2_0, (void*)&b2_0,
        (void*)&eps1, (void*)&w1_1, (void*)&b1_1, (void*)&w2_1, (void*)&b2_1,
        (void*)&binned, (void*)&gcursor, (void*)&dvec, (void*)&EW,
        (void*)&bc0, (void*)&wc1, (void*)&bc1, (void*)&out
    };

    hipLaunchCooperativeKernel((const void*)k_fused, dim3(NB), dim3(1024),
                               args, 0, stream);
}

// Round 6
// 158.946 us; speedup vs baseline: 1.9981x; 1.9981x over previous
//
#include <hip/hip_runtime.h>

#define N_NODES  100000
#define N_EDGES  1600000
#define HIDDEN   128
#define N_GRAPHS 2048
#define VOCAB    28
#define NB       512        // dst buckets of 196 nodes (512*196 = 100352)
#define NPB      196        // nodes per bucket
#define CAP      3600       // per-bucket capacity (E=3125, sigma~56 -> +8.5σ)
#define NBIN     512        // binning blocks
#define EPB      3125       // edges per binning block (512*3125 = 1.6M exact)
#define EPT      4          // ceil(3125/1024)
#define CSTR     29         // lcnt stride (gcd(29,32)=1 -> conflict-free)
#define MAGIC196 1402438302ULL  // ceil(2^38/196): b=(dst*M)>>38 exact for dst<1e9

// ---------------------------------------------------------------------------
// k_init: blocks 0..9: zero y_hat(2048)+gcursor(512); blocks 10..23:
// T = embed @ w1_0  [28,128] (3584 = 14*256).
// ---------------------------------------------------------------------------
__global__ __launch_bounds__(256) void k_init(float* __restrict__ out,
                                              int* __restrict__ gcursor,
                                              const float* __restrict__ embed,
                                              const float* __restrict__ w1_0,
                                              float* __restrict__ T) {
    const int bid = blockIdx.x, tid = threadIdx.x;
    if (bid < 10) {
        int i = bid * 256 + tid;
        if (i < N_GRAPHS) out[i] = 0.0f;
        else if (i < N_GRAPHS + NB) gcursor[i - N_GRAPHS] = 0;
    } else {
        int g = (bid - 10) * 256 + tid;            // < 3584
        int i = g >> 7, j = g & 127;
        float s = 0.f;
#pragma unroll 8
        for (int k = 0; k < HIDDEN; ++k)
            s += embed[i * HIDDEN + k] * w1_0[k * HIDDEN + j];
        T[g] = s;
    }
}

// ---------------------------------------------------------------------------
// k_bin: blocks [0,512): scan-free direct-scatter multisplit (2 blocks/CU).
//   pass1: LDS hist[512]; reserve: gbase=atomicAdd(gcursor);
//   pass2: lr=atomicAdd(lcur); binned[b*CAP+gbase+lr] = pk
//   packed: dl<<22 | vix<<17 | src   (dl<196: 8b, vix: 5b, src: 17b)
// blocks [512,516): EW = T @ w2_0 ; block 516: bc0/wc1/bc1 folds.
// ---------------------------------------------------------------------------
__global__ __launch_bounds__(1024) void k_bin(const int* __restrict__ esrc,
                                              const int* __restrict__ edst,
                                              const int* __restrict__ x_idx,
                                              unsigned* __restrict__ binned,
                                              int* __restrict__ gcursor,
                                              const float* __restrict__ T,
                                              const float* __restrict__ w2_0,
                                              const float* __restrict__ b1_0,
                                              const float* __restrict__ b2_0,
                                              const float* __restrict__ w1_1,
                                              const float* __restrict__ b1_1,
                                              const float* __restrict__ w2_1,
                                              const float* __restrict__ b2_1,
                                              float* __restrict__ EW,
                                              float* __restrict__ bc0,
                                              float* __restrict__ wc1,
                                              float* __restrict__ bc1) {
    const int tid = threadIdx.x;
    const int bid = blockIdx.x;

    if (bid >= NBIN) {
        if (bid < NBIN + 4) {                       // EW = T @ w2_0 [28,128]
            int g = (bid - NBIN) * 1024 + tid;
            if (g < VOCAB * HIDDEN) {
                int i = g >> 7, j = g & 127;
                float s = 0.f;
#pragma unroll 8
                for (int k = 0; k < HIDDEN; ++k)
                    s += T[i * HIDDEN + k] * w2_0[k * HIDDEN + j];
                EW[g] = s;
            }
        } else {                                    // bias / wc1 folds
            if (tid < 128) {
                float s = 0.f;
#pragma unroll 8
                for (int k = 0; k < HIDDEN; ++k)
                    s += b1_0[k] * w2_0[k * HIDDEN + tid];
                bc0[tid] = s + b2_0[tid];
                if (tid == 0) {
                    float q = 0.f;
                    for (int k = 0; k < HIDDEN; ++k) q += b1_1[k] * w2_1[k];
                    bc1[0] = q + b2_1[0];
                }
            } else if (tid < 256) {
                int i = tid - 128;
                float s = 0.f;
#pragma unroll 8
                for (int k = 0; k < HIDDEN; ++k)
                    s += w1_1[i * HIDDEN + k] * w2_1[k];
                wc1[i] = s;
            }
        }
        return;
    }

    __shared__ int hist[NB];
    __shared__ int lcur[NB];
    __shared__ int gbase[NB];

    if (tid < NB) { hist[tid] = 0; lcur[tid] = 0; }
    __syncthreads();

    unsigned mypk[EPT];
    short    myb[EPT];
#pragma unroll
    for (int i = 0; i < EPT; ++i) {
        int idx = i * 1024 + tid;
        myb[i] = -1;
        if (idx < EPB) {
            int e   = bid * EPB + idx;
            int dst = edst[e];
            int src = esrc[e];
            int b   = (int)(((unsigned long long)dst * MAGIC196) >> 38);
            int dl  = dst - b * NPB;                  // 0..195
            int vix = x_idx[src];                     // 0..27
            mypk[i] = ((unsigned)dl << 22) | ((unsigned)vix << 17) | (unsigned)src;
            myb[i]  = (short)b;
            atomicAdd(&hist[b], 1);
        }
    }
    __syncthreads();

    if (tid < NB) {
        int v = hist[tid];
        gbase[tid] = (v > 0) ? atomicAdd(&gcursor[tid], v) : 0;
    }
    __syncthreads();

#pragma unroll
    for (int i = 0; i < EPT; ++i) {
        if (myb[i] >= 0) {
            int b  = myb[i];
            int lr = atomicAdd(&lcur[b], 1);
            binned[(size_t)b * CAP + gbase[b] + lr] = mypk[i];
        }
    }
}

// ---------------------------------------------------------------------------
// k_layerC: one block (1024 thr) per bucket of 196 nodes; 22.7 KB LDS ->
// 2 blocks/CU, 32 waves/CU.
//   1) scan bucket edges -> LDS vocab histogram (stride-29, conflict-free)
//   2) lanes < 196: counts -> 28 float regs (static idx; self-term via
//      (v==xi) select), 32 float4 groups, wave-uniform EW/bc0/wc1 s_loads.
//   d[n] = dot(relu(sum_v cf_v*EW[v] + bc0), wc1)
// ---------------------------------------------------------------------------
__global__ __launch_bounds__(1024) void k_layerC(const unsigned* __restrict__ binned,
                                                 const int* __restrict__ gcursor,
                                                 const int* __restrict__ x_idx,
                                                 const float* __restrict__ EW,
                                                 const float* __restrict__ bc0,
                                                 const float* __restrict__ wc1,
                                                 const float* __restrict__ eps0,
                                                 float* __restrict__ d) {
    __shared__ int lcnt[NPB * CSTR];    // 22.7 KB

    const int tid = threadIdx.x;
    const int b   = blockIdx.x;

    for (int i = tid; i < NPB * CSTR; i += 1024) lcnt[i] = 0;
    __syncthreads();

    const int cnt = gcursor[b];
    const unsigned* bp = binned + (size_t)b * CAP;
    for (int i = tid; i < cnt; i += 1024) {
        unsigned pk = bp[i];
        atomicAdd(&lcnt[(pk >> 22) * CSTR + ((pk >> 17) & 31)], 1);
    }
    __syncthreads();

    if (tid >= NPB) return;

    const int n      = b * NPB + tid;
    const bool valid = (n < N_NODES);
    const int xi     = valid ? x_idx[n] : 0;
    const float s    = 1.0f + eps0[0];

    float cf[VOCAB];
#pragma unroll
    for (int v = 0; v < VOCAB; ++v)
        cf[v] = (float)lcnt[tid * CSTR + v] + ((v == xi) ? s : 0.0f);

    const float4* EW4 = reinterpret_cast<const float4*>(EW);   // uniform
    const float4* b04 = reinterpret_cast<const float4*>(bc0);
    const float4* w14 = reinterpret_cast<const float4*>(wc1);

    float dacc = 0.f;
#pragma unroll 1
    for (int f4 = 0; f4 < 32; ++f4) {
        float4 a = b04[f4];
#pragma unroll
        for (int v = 0; v < VOCAB; ++v) {
            float4 e = EW4[v * 32 + f4];
            a.x += cf[v] * e.x;
            a.y += cf[v] * e.y;
            a.z += cf[v] * e.z;
            a.w += cf[v] * e.w;
        }
        float4 w = w14[f4];
        dacc += fmaxf(a.x, 0.f) * w.x + fmaxf(a.y, 0.f) * w.y
              + fmaxf(a.z, 0.f) * w.z + fmaxf(a.w, 0.f) * w.w;
    }
    if (valid) d[n] = dacc;
}

// ---------------------------------------------------------------------------
// k_B2: one block (1024 thr) per bucket; ~8.8 KB LDS -> 2 blocks/CU.
// Layer-1 aggregation via LDS float atomics on racc[196] from L2-resident
// d[src] gathers. Fused x write + graph segment-sum (batch sorted).
// ---------------------------------------------------------------------------
__global__ __launch_bounds__(1024) void k_B2(const unsigned* __restrict__ binned,
                                             const int* __restrict__ gcursor,
                                             const float* __restrict__ d,
                                             const int* __restrict__ batch,
                                             const float* __restrict__ eps1,
                                             const float* __restrict__ bc1,
                                             float* __restrict__ out) {
    __shared__ float racc[NPB];
    __shared__ float gacc[N_GRAPHS];

    const int tid = threadIdx.x;
    const int b   = blockIdx.x;
    const int n0  = b * NPB;
    const int nlast = min(n0 + NPB - 1, N_NODES - 1);

    if (tid < NPB) racc[tid] = 0.f;
    const int g0 = batch[n0];
    const int g1 = batch[nlast];
    for (int g = g0 + tid; g <= g1; g += 1024) gacc[g] = 0.f;
    __syncthreads();

    const int cnt = gcursor[b];
    const unsigned* bp = binned + (size_t)b * CAP;
    for (int i = tid; i < cnt; i += 1024) {
        unsigned pk = bp[i];
        atomicAdd(&racc[pk >> 22], d[pk & 0x1FFFFu]);
    }
    __syncthreads();

    int n = n0 + tid;
    if (tid < NPB && n < N_NODES) {
        float r = (1.0f + eps1[0]) * d[n] + racc[tid] + bc1[0];
        out[N_GRAPHS + n] = r;
        atomicAdd(&gacc[batch[n]], r);
    }
    __syncthreads();
    for (int g = g0 + tid; g <= g1; g += 1024) {
        float v = gacc[g];
        if (v != 0.f) atomicAdd(&out[g], v);
    }
}

// ---------------------------------------------------------------------------
extern "C" void kernel_launch(void* const* d_in, const int* in_sizes, int n_in,
                              void* d_out, int out_size, void* d_ws, size_t ws_size,
                              hipStream_t stream) {
    const int*   x_idx = (const int*)d_in[0];
    const int*   esrc  = (const int*)d_in[1];
    const int*   edst  = (const int*)d_in[2];
    const int*   batch = (const int*)d_in[3];
    const float* embed = (const float*)d_in[4];
    const float* eps0  = (const float*)d_in[5];
    const float* w1_0  = (const float*)d_in[6];
    const float* b1_0  = (const float*)d_in[7];
    const float* w2_0  = (const float*)d_in[8];
    const float* b2_0  = (const float*)d_in[9];
    const float* eps1  = (const float*)d_in[10];
    const float* w1_1  = (const float*)d_in[11];
    const float* b1_1  = (const float*)d_in[12];
    const float* w2_1  = (const float*)d_in[13];
    const float* b2_1  = (const float*)d_in[14];

    float* out = (float*)d_out;

    // ws: [gcursor(512) | binned(NB*CAP) | dvec(100352) | T | EW | bc0 | wc1 | bc1]
    int*      gcursor = (int*)d_ws;                           // 512
    unsigned* binned  = (unsigned*)(gcursor + 512);           // 512*3600
    float*    dvec    = (float*)(binned + (size_t)NB * CAP);  // 100352
    float*    T       = dvec + 100352;                        // 3584
    float*    EW      = T + VOCAB * HIDDEN;                   // 3584
    float*    bc0     = EW + VOCAB * HIDDEN;                  // 128
    float*    wc1     = bc0 + HIDDEN;                         // 128
    float*    bc1     = wc1 + HIDDEN;                         // 1

    // zero y_hat+gcursor; T = embed @ w1_0
    k_init<<<24, 256, 0, stream>>>(out, gcursor, embed, w1_0, T);

    // bin edges (2 blocks/CU); EW/bias folds in extra blocks
    k_bin<<<NBIN + 5, 1024, 0, stream>>>(esrc, edst, x_idx, binned, gcursor,
                                         T, w2_0, b1_0, b2_0,
                                         w1_1, b1_1, w2_1, b2_1,
                                         EW, bc0, wc1, bc1);

    // layer 0 (+dot wc1): 512 blocks, 2/CU
    k_layerC<<<NB, 1024, 0, stream>>>(binned, gcursor, x_idx, EW, bc0, wc1, eps0, dvec);

    // layer 1 aggregation + fused outputs: 512 blocks, 2/CU
    k_B2<<<NB, 1024, 0, stream>>>(binned, gcursor, dvec, batch, eps1, bc1, out);
}